// Round 2
// baseline (1032.005 us; speedup 1.0000x reference)
//
#include <hip/hip_runtime.h>

// EMAVectorQuantizer eval forward, MI355X.
// Outputs (flat float32 in d_out): quantized[33554432] | loss[1] | idx_as_float[131072]
//
// N = 131072 rows, D = 256, K = 1024 codes.
// The checker's reference is a float32 NUMPY transcription of the jnp code:
//   d[n,k] = fl32( fl32(c_n + e2_k) - M[n,k] ),  M = (2*flat) @ cb.T (sgemm),
//   c_n  = np.sum(flat*flat, axis=1)  -- numpy PAIRWISE order (128+128 blocks,
//          8 stride-8 accumulators, tree combine),
//   idx = first-min argmin.
// At |c|~256 the fp32 grid (ULP ~3e-5) creates rounded TIES (~0.5% of rows) that
// np.argmin resolves by lowest k -- so we must replicate the fp32 rounding
// structure bit-exactly (c bit-exact; e2/gemm are insensitive to order jitter).

#define NROWS   131072
#define DDIM    256
#define KCODES  1024
#define RPB     128        // rows per block (vq_main)
#define KC      128        // codes per chunk
#define DC      32         // d per chunk
#define NKC     (KCODES / KC)
#define NDC     (DDIM / DC)
#define LOSS_OFF 33554432
#define IDX_OFF  33554433
#define LOSS_SCALE (1.25f / 33554432.f)

// ---------------- Kernel A: transpose codebook, e2[k] in numpy-pairwise fp32 order ---------------
__global__ void vq_prep(const float* __restrict__ cb, float* __restrict__ cbT,
                        float* __restrict__ e2, float* __restrict__ loss_slot) {
    __shared__ float ls[DDIM];
    const int b = blockIdx.x;          // code 0..1023
    const int t = threadIdx.x;         // 0..255 = d
    float v = cb[b * DDIM + t];
    cbT[(long)t * KCODES + b] = v;     // cbT[d][k]
    ls[t] = v;
    __syncthreads();
    if (t < 16) {
        #pragma clang fp contract(off)
        const int h = t >> 3, j = t & 7;           // 128-block half, chain id
        const float* base = &ls[h * 128 + j];
        float r = base[0] * base[0];               // a[j]
        #pragma unroll
        for (int i = 1; i < 16; ++i) {             // r[j] += a[8i+j], 15 sequential adds
            float ai = base[8 * i] * base[8 * i];
            r = r + ai;
        }
        float s1 = r  + __shfl_xor(r, 1);          // (r0+r1),(r2+r3),...
        float s2 = s1 + __shfl_xor(s1, 2);         // ((r0+r1)+(r2+r3)),...
        float s3 = s2 + __shfl_xor(s2, 4);         // block sum
        float c  = s3 + __shfl_xor(s3, 8);         // block0 + block1
        if (t == 0) e2[b] = c;
    }
    if (b == 0 && t == 0) *loss_slot = 0.f;
}

// ---------------- Kernel B: c_n = np.sum(x*x, axis=1) in exact numpy pairwise order --------------
__global__ __launch_bounds__(256) void vq_csum(const float* __restrict__ x,
                                               float* __restrict__ cvec) {
    __shared__ __align__(16) float xs[16][264];    // +8 pad: conflict-free chain reads
    const int t = threadIdx.x;
    const long row0 = (long)blockIdx.x * 16;
    #pragma unroll
    for (int it = 0; it < 4; ++it) {               // stage 16 rows x 256 f32, coalesced
        int task = t + 256 * it;                   // 0..1023 float4 slots
        int r = task >> 6, q = task & 63;
        const float4 v = *(const float4*)(x + (row0 + r) * DDIM + q * 4);
        *(float4*)&xs[r][q * 4] = v;
    }
    __syncthreads();
    {
        #pragma clang fp contract(off)
        const int rr = t >> 4, l = t & 15, h = l >> 3, j = l & 7;
        const float* base = &xs[rr][h * 128 + j];
        float r = base[0] * base[0];
        #pragma unroll
        for (int i = 1; i < 16; ++i) {
            float ai = base[8 * i] * base[8 * i];
            r = r + ai;
        }
        float s1 = r  + __shfl_xor(r, 1);
        float s2 = s1 + __shfl_xor(s1, 2);
        float s3 = s2 + __shfl_xor(s2, 4);
        float c  = s3 + __shfl_xor(s3, 8);
        if (l == 0) cvec[row0 + rr] = c;
    }
}

// ---------------- Kernel C: main fused distance/argmin/gather/loss ------------------------------
__global__ __launch_bounds__(256, 2) void vq_main(
    const float* __restrict__ x, const float* __restrict__ cb,
    const float* __restrict__ cbT, const float* __restrict__ e2g,
    const float* __restrict__ cvec, float* __restrict__ out) {

    __shared__ __align__(16) float As[DC][RPB];   // As[d][row], 16 KB
    __shared__ __align__(16) float Bs[DC][KC];    // Bs[d][code], 16B-slot swizzled, 16 KB
    __shared__ float e2s[KCODES];                 // 4 KB
    __shared__ int   idxs[RPB];
    __shared__ float redbuf[4];

    const int t = threadIdx.x;
    const int i = t >> 4;           // row-thread   0..15 (8 rows each)
    const int j = t & 15;           // code-thread  0..15 (8 codes each)
    const long row0 = (long)blockIdx.x * RPB;

    for (int s = t; s < KCODES; s += 256) e2s[s] = e2g[s];

    float cr8[8];
    #pragma unroll
    for (int r = 0; r < 8; ++r) cr8[r] = cvec[row0 + i * 8 + r];

    float bd[8]; int bi[8];
    #pragma unroll
    for (int r = 0; r < 8; ++r) { bd[r] = 3.4e38f; bi[r] = 0x7fffffff; }

    // swizzled byte offsets of this thread's two 16B code slots (logical slots 2j, 2j+1)
    const int s0 = 2 * j, s1 = 2 * j + 1;
    const int so0 = (s0 ^ ((s0 >> 4) & 1)) * 16;
    const int so1 = (s1 ^ ((s1 >> 4) & 1)) * 16;

    for (int kc = 0; kc < NKC; ++kc) {
        float acc[8][8];
        #pragma unroll
        for (int r = 0; r < 8; ++r)
            #pragma unroll
            for (int c = 0; c < 8; ++c) acc[r][c] = 0.f;

        for (int dc = 0; dc < NDC; ++dc) {
            __syncthreads();
            // ---- stage As (transpose x tile)
            #pragma unroll
            for (int ss = 0; ss < 4; ++ss) {
                int task = t + 256 * ss;
                int r  = task & 127;
                int d4 = task >> 7;                       // 0..7
                const float4 xv = *(const float4*)(x + (row0 + r) * DDIM + dc * DC + d4 * 4);
                As[d4 * 4 + 0][r] = xv.x;
                As[d4 * 4 + 1][r] = xv.y;
                As[d4 * 4 + 2][r] = xv.z;
                As[d4 * 4 + 3][r] = xv.w;
            }
            // ---- stage Bs from pre-transposed codebook (coalesced), swizzled slot store
            #pragma unroll
            for (int ss = 0; ss < 4; ++ss) {
                int task = t + 256 * ss;
                int d  = task >> 5;                       // 0..31
                int sl = task & 31;                       // logical 16B slot
                int slp = sl ^ ((sl >> 4) & 1);           // swizzled slot
                const float4 bvv = *(const float4*)(cbT + (long)(dc * DC + d) * KCODES + kc * KC + sl * 4);
                *(float4*)&Bs[d][slp * 4] = bvv;
            }
            __syncthreads();

            const char* BsBase = (const char*)&Bs[0][0];
            #pragma unroll 8
            for (int dd = 0; dd < DC; ++dd) {
                const float4 a0 = *(const float4*)&As[dd][i * 8];
                const float4 a1 = *(const float4*)&As[dd][i * 8 + 4];
                const float4 b0 = *(const float4*)(BsBase + dd * (KC * 4) + so0);
                const float4 b1 = *(const float4*)(BsBase + dd * (KC * 4) + so1);
                const float av[8] = {a0.x, a0.y, a0.z, a0.w, a1.x, a1.y, a1.z, a1.w};
                const float bw[8] = {b0.x, b0.y, b0.z, b0.w, b1.x, b1.y, b1.z, b1.w};
                #pragma unroll
                for (int r = 0; r < 8; ++r)
                    #pragma unroll
                    for (int c = 0; c < 8; ++c)
                        acc[r][c] = fmaf(av[r], bw[c], acc[r][c]);
            }
        }

        // ---- finalize chunk: d = fl(fl(c + e2) - 2*dot), replicate np fp32 rounding ----
        {
            #pragma clang fp contract(off)
            #pragma unroll
            for (int c = 0; c < 8; ++c) {
                const int k = kc * KC + j * 8 + c;
                const float e2v = e2s[k];
                #pragma unroll
                for (int r = 0; r < 8; ++r) {
                    float S  = cr8[r] + e2v;              // fl(c + e2)  (ULP ~3e-5 grid!)
                    float dv = S - 2.0f * acc[r][c];      // 2*acc exact; single rounding
                    if (dv < bd[r]) { bd[r] = dv; bi[r] = k; }   // k ascending: first-min wins
                }
            }
        }
    }

    // ---- merge argmin across the 16 code-threads of each row group (tie -> lowest k)
    #pragma unroll
    for (int r = 0; r < 8; ++r) {
        float v1 = bd[r];
        int   i1 = bi[r];
        #pragma unroll
        for (int off = 1; off < 16; off <<= 1) {
            float ov1 = __shfl_xor(v1, off);
            int   oi1 = __shfl_xor(i1, off);
            if (ov1 < v1 || (ov1 == v1 && oi1 < i1)) { v1 = ov1; i1 = oi1; }
        }
        if (j == 0) idxs[i * 8 + r] = i1;
    }
    __syncthreads();

    // ---- gather quantized rows, replicate out0 = fl(x + fl(q - x)), accumulate loss
    float sq = 0.f;
    {
        #pragma clang fp contract(off)
        #pragma unroll 4
        for (int it = 0; it < 32; ++it) {
            int task = t + 256 * it;
            int r  = task >> 6;                            // whole wave on one row -> coalesced
            int d4 = task & 63;
            int idx = idxs[r];
            const float4 q4 = *(const float4*)(cb + (long)idx * DDIM + d4 * 4);
            const float4 x4 = *(const float4*)(x + (row0 + r) * DDIM + d4 * 4);
            float d0 = q4.x - x4.x, d1 = q4.y - x4.y, d2 = q4.z - x4.z, d3 = q4.w - x4.w;
            float4 o4;
            o4.x = x4.x + d0; o4.y = x4.y + d1; o4.z = x4.z + d2; o4.w = x4.w + d3;
            *(float4*)(out + (row0 + r) * DDIM + d4 * 4) = o4;
            sq += d0 * d0 + d1 * d1 + d2 * d2 + d3 * d3;
        }
    }
    #pragma unroll
    for (int off = 32; off; off >>= 1) sq += __shfl_down(sq, off);
    if ((t & 63) == 0) redbuf[t >> 6] = sq;
    __syncthreads();
    if (t == 0)
        atomicAdd(out + LOSS_OFF, (redbuf[0] + redbuf[1] + redbuf[2] + redbuf[3]) * LOSS_SCALE);
    if (t < RPB) out[IDX_OFF + row0 + t] = (float)idxs[t];
}

// ---------------- host ---------------------------------------------------------------------------
extern "C" void kernel_launch(void* const* d_in, const int* in_sizes, int n_in,
                              void* d_out, int out_size, void* d_ws, size_t ws_size,
                              hipStream_t stream) {
    const float* x  = (const float*)d_in[0];   // [32,256,64,64] fp32 -> flat [131072][256]
    const float* cb = (const float*)d_in[1];   // [1024,256] fp32
    float* out = (float*)d_out;
    float* ws  = (float*)d_ws;

    float* cbT  = ws;                              // 262144 floats (1 MB)
    float* e2   = ws + 262144;                     // 1024 floats
    float* cvec = ws + 262144 + 1024;              // 131072 floats (||x||^2 per row, np order)

    vq_prep<<<KCODES, 256, 0, stream>>>(cb, cbT, e2, out + LOSS_OFF);
    vq_csum<<<NROWS / 16, 256, 0, stream>>>(x, cvec);
    vq_main<<<NROWS / RPB, 256, 0, stream>>>(x, cb, cbT, e2, cvec, out);
}